// Round 7
// baseline (766.476 us; speedup 1.0000x reference)
//
#include <hip/hip_runtime.h>
#include <math.h>

#define NPTS 400000
#define K27  27
#define WTILE 3072     // shorts per k-tile in Wt (48 x 64, linear)

typedef unsigned short u16;
typedef __bf16 bf16x8 __attribute__((ext_vector_type(8)));
typedef float  f32x4  __attribute__((ext_vector_type(4)));

__device__ __forceinline__ u16 f2bf(float f) {
    unsigned u = __float_as_uint(f);
    u += 0x7FFFu + ((u >> 16) & 1u);   // RNE round to bf16
    return (u16)(u >> 16);
}
__device__ __forceinline__ unsigned pack2(float lo, float hi) {
    return (unsigned)f2bf(lo) | ((unsigned)f2bf(hi) << 16);
}
__device__ __forceinline__ bf16x8 pack8(float4 x, float4 y) {
    union { uint4 u; bf16x8 v; } r;
    r.u.x = pack2(x.x, x.y); r.u.y = pack2(x.z, x.w);
    r.u.z = pack2(y.x, y.y); r.u.w = pack2(y.z, y.w);
    return r.v;
}
__device__ __forceinline__ bf16x8 zero8() {
    union { uint4 u; bf16x8 v; } r;
    r.u.x = 0; r.u.y = 0; r.u.z = 0; r.u.w = 0;
    return r.v;
}

// ---------------------------------------------------------------------------
// prep: W1 [27][64][38] / W2 [27][38][38] -> [27][WTILE] bf16 tiles
// (48x64 n-major, k-contig, zero-padded, LINEAR layout — B-fragments are
// read directly from global in the main kernel, no LDS).
// Also zeroes the padding row (index NPTS) of h and Fb so the gather path
// needs no branch: idx==NPTS reads a zero row.
// ---------------------------------------------------------------------------
__global__ void prep_w(const float* __restrict__ W1, const float* __restrict__ W2,
                       u16* __restrict__ W1t, u16* __restrict__ W2t,
                       u16* __restrict__ hpad, u16* __restrict__ fpad)
{
    int i = blockIdx.x * 256 + threadIdx.x;
    if (i < 64) {                 // one 64-short row each
        hpad[i] = 0;
        if (fpad) fpad[i] = 0;
    }
    const int TOT = K27 * 48 * 64;
    if (i >= TOT) return;
    int k  = i / (48 * 64);
    int r  = i % (48 * 64);
    int n  = r >> 6;    // 0..47 (out channel)
    int kc = r & 63;    // 0..63 (in channel)
    u16 w1 = 0, w2 = 0;
    if (n < 38) {
        w1 = f2bf(W1[(k * 64 + kc) * 38 + n]);
        if (kc < 38) w2 = f2bf(W2[(k * 38 + kc) * 38 + n]);
    }
    W1t[k * WTILE + r] = w1;
    W2t[k * WTILE + r] = w2;
}

// ---------------------------------------------------------------------------
// prep: features fp32 [N][64] -> bf16 [N][64]  (8 elems / thread)
// ---------------------------------------------------------------------------
__global__ void prep_feat(const float* __restrict__ F, u16* __restrict__ Fb)
{
    size_t i = (size_t)blockIdx.x * 256 + threadIdx.x;
    const size_t TOT = (size_t)NPTS * 64 / 8;              // 3,200,000 exact
    if (i >= TOT) return;
    const float4* fp = (const float4*)(F + i * 8);
    float4 a = fp[0], b = fp[1];
    uint4 v;
    v.x = pack2(a.x, a.y); v.y = pack2(a.z, a.w);
    v.z = pack2(b.x, b.y); v.w = pack2(b.z, b.w);
    *(uint4*)(Fb + i * 8) = v;
}

// ---------------------------------------------------------------------------
// gather-GEMM layer. Round-7: FULLY DECOUPLED WAVES.
//   - 1 wave per block (64 thr), 12500 blocks, no LDS, NO BARRIERS at all.
//   - B-fragments read directly from global Wt (6KB/k, L1-hot: every wave
//     on the CU reads the same tile, roughly in phase).
//   - A-fragments: direct global gather, reg ping/pong 2-deep (R4's proven
//     sched_barrier-pinned structure); idx prefetched 2 iters ahead.
//   - Compiler's counted vmcnt before the MFMAs retires only the B-loads;
//     A/idx prefetches stay in flight across iterations.
// Wave owns 32 rows (2 row-tiles of 16). ~104 VGPR live -> 4 waves/SIMD.
// LAYER==1: -> GELU -> h bf16 [N+1][64] (cols 48..63 zeroed)
// LAYER==2: -> fp32 out [N][38]
// ---------------------------------------------------------------------------
template<int LAYER, bool BF16IN>
__global__ __launch_bounds__(64, 4)
void spconv(const void* __restrict__ in_, const int* __restrict__ nbr,
            const u16* __restrict__ Wt, void* __restrict__ out_)
{
    const int lane = threadIdx.x & 63;
    const int quad = lane >> 4;
    const int l16  = lane & 15;

    // bijective XCD-chunk swizzle (nwg=12500, q=1562, r=4)
    int bid;
    {
        const int nwg = NPTS / 32, q = nwg / 8, r = nwg % 8;
        int x = blockIdx.x % 8, o = blockIdx.x / 8;
        bid = (x < r ? x * (q + 1) : r * (q + 1) + (x - r) * q) + o;
    }
    const int rbase = bid * 32;                // 12500*32 == 400000
    // per-lane W base (shorts): row (l16) x 64 + quad*8
    const u16* wlane = Wt + l16 * 64 + quad * 8;

    f32x4 acc[2][3] = {};
    bf16x8 aP[2][2], aQ[2][2];     // 2-deep A ping/pong
    int iP[2], iQ[2];              // idx ping/pong

    #define GATHER_BF16(dst, ids)                                             \
        {                                                                     \
            const u16* F = (const u16*)in_;                                   \
            _Pragma("unroll")                                                 \
            for (int rt = 0; rt < 2; ++rt) {                                  \
                const u16* rowp = F + (size_t)(ids)[rt] * 64 + quad * 8;      \
                (dst)[rt][0] = *(const bf16x8*)(rowp);                        \
                (dst)[rt][1] = *(const bf16x8*)(rowp + 32);                   \
            }                                                                 \
        }
    #define GATHER_F32(dst, ids)                                              \
        {                                                                     \
            const float* F = (const float*)in_;                               \
            _Pragma("unroll")                                                 \
            for (int rt = 0; rt < 2; ++rt) {                                  \
                if ((ids)[rt] < NPTS) {                                       \
                    const float* rowp = F + (size_t)(ids)[rt] * 64 + quad * 8;\
                    float4 f0 = *(const float4*)(rowp);                       \
                    float4 f1 = *(const float4*)(rowp + 4);                   \
                    float4 f2 = *(const float4*)(rowp + 32);                  \
                    float4 f3 = *(const float4*)(rowp + 36);                  \
                    (dst)[rt][0] = pack8(f0, f1);                             \
                    (dst)[rt][1] = pack8(f2, f3);                             \
                } else {                                                      \
                    (dst)[rt][0] = zero8();                                   \
                    (dst)[rt][1] = zero8();                                   \
                }                                                             \
            }                                                                 \
        }
    #define GATHER(dst, ids) { if (BF16IN) GATHER_BF16(dst, ids) else GATHER_F32(dst, ids) }

    // ---------------- prologue ----------------
    #pragma unroll
    for (int rt = 0; rt < 2; ++rt) iP[rt] = nbr[rbase + rt * 16 + l16];
    GATHER(aP, iP);                                   // A_0
    #pragma unroll
    for (int rt = 0; rt < 2; ++rt) iQ[rt] = nbr[(size_t)NPTS + rbase + rt * 16 + l16];

    // ---------------- main loop (no barriers, no LDS) ----------------
    // ITER(k): region1: load B_k (6 global, L1-hot) + idx_{k+2} + gather
    //          A_{k+1} via ICUR; region2: 12 MFMAs on ACUR/B_k.
    // Compiler emits vmcnt(6) before the MFMAs (B done, A/idx in flight).
    #define ITER(KK, ACUR, ANXT, ICUR, INXT)                                  \
      {                                                                       \
        const int k_ = (KK);                                                  \
        bf16x8 bfr[3][2];                                                     \
        {                                                                     \
            const u16* wk = wlane + (size_t)k_ * WTILE;                       \
            _Pragma("unroll")                                                 \
            for (int nt = 0; nt < 3; ++nt)                                    \
                _Pragma("unroll")                                             \
                for (int ks = 0; ks < 2; ++ks)                                \
                    bfr[nt][ks] = *(const bf16x8*)(wk + nt * 1024 + ks * 32); \
        }                                                                     \
        {                                                                     \
            int kf = k_ + 2; if (kf > K27 - 1) kf = K27 - 1;                  \
            const int* nr = nbr + (size_t)kf * NPTS + rbase;                  \
            _Pragma("unroll")                                                 \
            for (int rt = 0; rt < 2; ++rt) INXT[rt] = nr[rt * 16 + l16];      \
        }                                                                     \
        GATHER(ANXT, ICUR);                                                   \
        __builtin_amdgcn_sched_barrier(0);                                    \
        __builtin_amdgcn_s_setprio(1);                                        \
        _Pragma("unroll")                                                     \
        for (int ks = 0; ks < 2; ++ks)                                        \
            _Pragma("unroll")                                                 \
            for (int rt = 0; rt < 2; ++rt)                                    \
                _Pragma("unroll")                                             \
                for (int nt = 0; nt < 3; ++nt)                                \
                    acc[rt][nt] = __builtin_amdgcn_mfma_f32_16x16x32_bf16(    \
                        ACUR[rt][ks], bfr[nt][ks], acc[rt][nt], 0, 0, 0);     \
        __builtin_amdgcn_s_setprio(0);                                        \
        __builtin_amdgcn_sched_barrier(0);                                    \
      }

    for (int k = 0; k < K27 - 1; k += 2) {   // 13 pairs: k = 0..25
        ITER(k,     aP, aQ, iQ, iP);
        ITER(k + 1, aQ, aP, iP, iQ);
    }
    ITER(K27 - 1, aP, aQ, iQ, iP);           // k = 26

    // ---------------- epilogue (C layout: col = l16, row = quad*4 + r) ----
    if (LAYER == 1) {
        u16* h = (u16*)out_;
        #pragma unroll
        for (int rt = 0; rt < 2; ++rt) {
            #pragma unroll
            for (int r = 0; r < 4; ++r) {
                size_t ro = (size_t)(rbase + rt * 16 + quad * 4 + r) * 64;
                #pragma unroll
                for (int nt = 0; nt < 3; ++nt) {
                    float x = acc[rt][nt][r];
                    float g = 0.5f * x * (1.0f + erff(x * 0.70710678118654752f));
                    h[ro + nt * 16 + l16] = f2bf(g);
                }
                h[ro + 48 + l16] = 0;      // zero pad cols 48..63
            }
        }
    } else {
        float* out = (float*)out_;
        #pragma unroll
        for (int rt = 0; rt < 2; ++rt) {
            #pragma unroll
            for (int nt = 0; nt < 3; ++nt) {
                int col = nt * 16 + l16;
                if (col < 38) {
                    #pragma unroll
                    for (int r = 0; r < 4; ++r) {
                        int row = rbase + rt * 16 + quad * 4 + r;
                        out[(size_t)row * 38 + col] = acc[rt][nt][r];
                    }
                }
            }
        }
    }
    #undef ITER
    #undef GATHER
    #undef GATHER_BF16
    #undef GATHER_F32
}

// ---------------------------------------------------------------------------
extern "C" void kernel_launch(void* const* d_in, const int* in_sizes, int n_in,
                              void* d_out, int out_size, void* d_ws, size_t ws_size,
                              hipStream_t stream)
{
    const float* feat = (const float*)d_in[0];   // [N][64] fp32
    const int*   nbr  = (const int*)  d_in[1];   // [27][N] int32, N == pad idx
    const float* W1   = (const float*)d_in[2];   // [27][64][38]
    const float* W2   = (const float*)d_in[3];   // [27][38][38]

    const size_t hbytes = (size_t)(NPTS + 1) * 64 * 2;   // h incl. zero pad row
    const size_t wbytes = (size_t)K27 * WTILE * 2;       // 165,888

    char* ws  = (char*)d_ws;
    u16* h    = (u16*)ws;
    u16* W1t  = (u16*)(ws + hbytes);
    u16* W2t  = (u16*)(ws + hbytes + wbytes);
    u16* Fb   = (u16*)(ws + hbytes + 2 * wbytes);
    const bool full = ws_size >= hbytes * 2 + 2 * wbytes;   // bf16 feature copy fits?

    prep_w<<<(K27 * 48 * 64 + 255) / 256, 256, 0, stream>>>(
        W1, W2, W1t, W2t,
        h + (size_t)NPTS * 64,
        full ? Fb + (size_t)NPTS * 64 : (u16*)nullptr);

    const int nblk = NPTS / 32;   // 12500, exact
    if (full) {
        prep_feat<<<(int)(((size_t)NPTS * 64 / 8 + 255) / 256), 256, 0, stream>>>(feat, Fb);
        spconv<1, true ><<<nblk, 64, 0, stream>>>(Fb,   nbr, W1t, h);
    } else {
        spconv<1, false><<<nblk, 64, 0, stream>>>(feat, nbr, W1t, h);
    }
    spconv<2, true ><<<nblk, 64, 0, stream>>>(h, nbr, W2t, d_out);
}

// Round 8
// 417.366 us; speedup vs baseline: 1.8365x; 1.8365x over previous
//
#include <hip/hip_runtime.h>
#include <math.h>

#define NPTS 400000
#define K27  27
#define WSTRIDE 4096   // shorts per k-tile in Wt (48*64=3072 used + pad -> 8KB)

typedef unsigned short u16;
typedef __bf16 bf16x8 __attribute__((ext_vector_type(8)));
typedef float  f32x4  __attribute__((ext_vector_type(4)));
typedef __attribute__((address_space(1))) void gvoid;
typedef __attribute__((address_space(3))) void lvoid;

__device__ __forceinline__ u16 f2bf(float f) {
    unsigned u = __float_as_uint(f);
    u += 0x7FFFu + ((u >> 16) & 1u);   // RNE round to bf16
    return (u16)(u >> 16);
}
__device__ __forceinline__ unsigned pack2(float lo, float hi) {
    return (unsigned)f2bf(lo) | ((unsigned)f2bf(hi) << 16);
}
__device__ __forceinline__ bf16x8 pack8(float4 x, float4 y) {
    union { uint4 u; bf16x8 v; } r;
    r.u.x = pack2(x.x, x.y); r.u.y = pack2(x.z, x.w);
    r.u.z = pack2(y.x, y.y); r.u.w = pack2(y.z, y.w);
    return r.v;
}
__device__ __forceinline__ bf16x8 zero8() {
    union { uint4 u; bf16x8 v; } r;
    r.u.x = 0; r.u.y = 0; r.u.z = 0; r.u.w = 0;
    return r.v;
}

// ---------------------------------------------------------------------------
// prep: W1 [27][64][38] / W2 [27][38][38] -> [27][WSTRIDE] bf16 tiles
// (48x64 n-major, zero-padded) with the LDS XOR-swizzle PRE-APPLIED:
//   short-offset o = n*64+kc stored at o ^ ((n&7)<<3).
// Staging copies linearly; the kernel's ds_read applies the same XOR.
// Also zeroes the padding row (index NPTS) of h and Fb.
// ---------------------------------------------------------------------------
__global__ void prep_w(const float* __restrict__ W1, const float* __restrict__ W2,
                       u16* __restrict__ W1t, u16* __restrict__ W2t,
                       u16* __restrict__ hpad, u16* __restrict__ fpad)
{
    int i = blockIdx.x * 256 + threadIdx.x;
    if (i < 64) {                 // one 64-short row each
        hpad[i] = 0;
        if (fpad) fpad[i] = 0;
    }
    const int TOT = K27 * 48 * 64;
    if (i >= TOT) return;
    int k  = i / (48 * 64);
    int r  = i % (48 * 64);
    int n  = r >> 6;    // 0..47 (out channel)
    int kc = r & 63;    // 0..63 (in channel)
    u16 w1 = 0, w2 = 0;
    if (n < 38) {
        w1 = f2bf(W1[(k * 64 + kc) * 38 + n]);
        if (kc < 38) w2 = f2bf(W2[(k * 38 + kc) * 38 + n]);
    }
    int os = r ^ ((n & 7) << 3);          // pre-swizzled position
    W1t[k * WSTRIDE + os] = w1;
    W2t[k * WSTRIDE + os] = w2;
}

// ---------------------------------------------------------------------------
// prep: features fp32 [N][64] -> bf16 [N][64]  (8 elems / thread)
// ---------------------------------------------------------------------------
__global__ void prep_feat(const float* __restrict__ F, u16* __restrict__ Fb)
{
    size_t i = (size_t)blockIdx.x * 256 + threadIdx.x;
    const size_t TOT = (size_t)NPTS * 64 / 8;              // 3,200,000 exact
    if (i >= TOT) return;
    const float4* fp = (const float4*)(F + i * 8);
    float4 a = fp[0], b = fp[1];
    uint4 v;
    v.x = pack2(a.x, a.y); v.y = pack2(a.z, a.w);
    v.z = pack2(b.x, b.y); v.w = pack2(b.z, b.w);
    *(uint4*)(Fb + i * 8) = v;
}

// ---------------------------------------------------------------------------
// gather-GEMM layer. Round-8: in-order-retire-safe schedule.
// Per-wave VMEM issue order per iter k (the invariant that makes it work):
//   r0: load W[k+3] -> regs            (OLDEST of this iter)
//   r1: B_k ds_read; idx_{k+3}; gather A_{k+2}
//   r2: MFMA on A_k (compiler vmcnt: A_k is 2 iters old -> retired free)
//   r3: s_barrier (single barrier/iter)
//   r4: vmcnt(14) -> retires ONLY W[k+2]-loads (oldest outstanding);
//       ds_write W[k+2] regs -> buf[k&1]
// A-gathers are never force-retired early: true 2-iter slack (~L3 latency).
// Block = 256 thr (4 waves) x 32 rows/wave = 128 rows; grid 3125 exact.
// LAYER==1: -> GELU -> h bf16 [N+1][64] (cols 48..63 zeroed)
// LAYER==2: -> fp32 out [N][38]
// ---------------------------------------------------------------------------
template<int LAYER, bool BF16IN>
__global__ __launch_bounds__(256, 3)
void spconv(const void* __restrict__ in_, const int* __restrict__ nbr,
            const u16* __restrict__ Wt, void* __restrict__ out_)
{
    __shared__ __align__(16) u16 wbuf[2][WSTRIDE];   // 2 x 8192 B

    const int t    = threadIdx.x;
    const int wave = t >> 6;
    const int lane = t & 63;
    const int quad = lane >> 4;
    const int l16  = lane & 15;

    // bijective XCD-chunk swizzle (nwg=3125, nwg%8=5 -> m204 variant)
    int bid;
    {
        const int nwg = NPTS / 128, q = nwg / 8, r = nwg % 8;
        int x = blockIdx.x % 8, o = blockIdx.x / 8;
        bid = (x < r ? x * (q + 1) : r * (q + 1) + (x - r) * q) + o;
    }
    const int rbase = bid * 128 + wave * 32;   // 3125*128 == 400000
    const int swz   = (l16 & 7) << 3;          // B-read swizzle (shorts)

    f32x4 acc[2][3] = {};
    bf16x8 aP[2][2], aQ[2][2], aR[2][2];   // A_k ring: slot = k % 3
    int iP[2], iQ[2];                      // idx_{k+2} ring: slot = k & 1
    uint4 wA0, wA1, wB0, wB1;              // W[k+2]-data ring: slot = k & 1

    #define GATHER_BF16(dst, ids)                                             \
        {                                                                     \
            const u16* F = (const u16*)in_;                                   \
            _Pragma("unroll")                                                 \
            for (int rt = 0; rt < 2; ++rt) {                                  \
                const u16* rowp = F + (size_t)(ids)[rt] * 64 + quad * 8;      \
                (dst)[rt][0] = *(const bf16x8*)(rowp);                        \
                (dst)[rt][1] = *(const bf16x8*)(rowp + 32);                   \
            }                                                                 \
        }
    #define GATHER_F32(dst, ids)                                              \
        {                                                                     \
            const float* F = (const float*)in_;                               \
            _Pragma("unroll")                                                 \
            for (int rt = 0; rt < 2; ++rt) {                                  \
                if ((ids)[rt] < NPTS) {                                       \
                    const float* rowp = F + (size_t)(ids)[rt] * 64 + quad * 8;\
                    float4 f0 = *(const float4*)(rowp);                       \
                    float4 f1 = *(const float4*)(rowp + 4);                   \
                    float4 f2 = *(const float4*)(rowp + 32);                  \
                    float4 f3 = *(const float4*)(rowp + 36);                  \
                    (dst)[rt][0] = pack8(f0, f1);                             \
                    (dst)[rt][1] = pack8(f2, f3);                             \
                } else {                                                      \
                    (dst)[rt][0] = zero8();                                   \
                    (dst)[rt][1] = zero8();                                   \
                }                                                             \
            }                                                                 \
        }
    #define GATHER(dst, ids) { if (BF16IN) GATHER_BF16(dst, ids) else GATHER_F32(dst, ids) }

    // prologue-only LDS staging (outside steady-state queue accounting)
    #define STAGE_W_LDS(KW, BSEL)                                             \
        {                                                                     \
            const u16* g_ = Wt + (size_t)(KW) * WSTRIDE + t * 8;              \
            u16* l_ = &wbuf[(BSEL)][t * 8];                                   \
            __builtin_amdgcn_global_load_lds((gvoid*)(g_),                    \
                                             (lvoid*)(l_), 16, 0, 0);         \
            __builtin_amdgcn_global_load_lds((gvoid*)(g_ + 2048),             \
                                             (lvoid*)(l_ + 2048), 16, 0, 0);  \
        }

    // ---------------- prologue ----------------
    {
        int i0[2], i1[2];
        #pragma unroll
        for (int rt = 0; rt < 2; ++rt) i0[rt] = nbr[rbase + rt * 16 + l16];
        GATHER(aP, i0);                               // A_0
        #pragma unroll
        for (int rt = 0; rt < 2; ++rt) i1[rt] = nbr[(size_t)NPTS + rbase + rt * 16 + l16];
        GATHER(aQ, i1);                               // A_1
        #pragma unroll
        for (int rt = 0; rt < 2; ++rt) iP[rt] = nbr[(size_t)2 * NPTS + rbase + rt * 16 + l16];
        const uint4* wp = (const uint4*)(Wt + (size_t)2 * WSTRIDE + t * 16);
        wA0 = wp[0]; wA1 = wp[1];                     // W[2] data
        STAGE_W_LDS(0, 0);
        STAGE_W_LDS(1, 1);
    }
    __builtin_amdgcn_sched_barrier(0);
    asm volatile("s_waitcnt vmcnt(0) lgkmcnt(0)" ::: "memory");
    __builtin_amdgcn_s_barrier();
    __builtin_amdgcn_sched_barrier(0);

    // ---------------- main loop ----------------
    // ITER(k, ACUR, AISS, ICUR, ILOAD, WWR0, WWR1, WLD0, WLD1)
    #define ITER(KK, ACUR, AISS, ICUR, ILOAD, WWR0, WWR1, WLD0, WLD1)         \
      {                                                                       \
        const int k_ = (KK);                                                  \
        /* r0: W[k+3] -> regs (MUST be oldest VMEM of this iter) */           \
        {                                                                     \
            int kw = k_ + 3; if (kw > K27 - 1) kw = K27 - 1;                  \
            const uint4* wp = (const uint4*)(Wt + (size_t)kw * WSTRIDE + t * 16);\
            WLD0 = wp[0]; WLD1 = wp[1];                                       \
        }                                                                     \
        __builtin_amdgcn_sched_barrier(0);                                    \
        /* r1: B ds_read + idx_{k+3} + gather A_{k+2} */                      \
        bf16x8 bfr[3][2];                                                     \
        {                                                                     \
            const u16* wb = &wbuf[k_ & 1][0];                                 \
            _Pragma("unroll")                                                 \
            for (int nt = 0; nt < 3; ++nt)                                    \
                _Pragma("unroll")                                             \
                for (int ks = 0; ks < 2; ++ks)                                \
                    bfr[nt][ks] = *(const bf16x8*)&wb[(nt * 16 + l16) * 64    \
                                        + ((ks * 32 + quad * 8) ^ swz)];      \
        }                                                                     \
        {                                                                     \
            int kf = k_ + 3; if (kf > K27 - 1) kf = K27 - 1;                  \
            const int* nr = nbr + (size_t)kf * NPTS + rbase;                  \
            _Pragma("unroll")                                                 \
            for (int rt = 0; rt < 2; ++rt) ILOAD[rt] = nr[rt * 16 + l16];     \
        }                                                                     \
        GATHER(AISS, ICUR);                                                   \
        __builtin_amdgcn_sched_barrier(0);                                    \
        /* r2: MFMA on A_k (2 iters old -> already retired, no stall) */      \
        __builtin_amdgcn_s_setprio(1);                                        \
        _Pragma("unroll")                                                     \
        for (int ks = 0; ks < 2; ++ks)                                        \
            _Pragma("unroll")                                                 \
            for (int rt = 0; rt < 2; ++rt)                                    \
                _Pragma("unroll")                                             \
                for (int nt = 0; nt < 3; ++nt)                                \
                    acc[rt][nt] = __builtin_amdgcn_mfma_f32_16x16x32_bf16(    \
                        ACUR[rt][ks], bfr[nt][ks], acc[rt][nt], 0, 0, 0);     \
        __builtin_amdgcn_s_setprio(0);                                        \
        __builtin_amdgcn_sched_barrier(0);                                    \
        /* r3: single barrier (all waves done reading buf[k&1]) */            \
        __builtin_amdgcn_s_barrier();                                         \
        __builtin_amdgcn_sched_barrier(0);                                    \
        /* r4: retire ONLY W[k+2] loads (oldest), publish to LDS */           \
        if (BF16IN) { asm volatile("s_waitcnt vmcnt(14)" ::: "memory"); }     \
        else        { asm volatile("s_waitcnt vmcnt(22)" ::: "memory"); }     \
        __builtin_amdgcn_sched_barrier(0);                                    \
        {                                                                     \
            uint4* wb = (uint4*)&wbuf[k_ & 1][t * 16];                        \
            wb[0] = WWR0; wb[1] = WWR1;                                       \
        }                                                                     \
        __builtin_amdgcn_sched_barrier(0);                                    \
      }

    for (int k = 0; k < 24; k += 6) {
        ITER(k + 0, aP, aR, iP, iQ, wA0, wA1, wB0, wB1);
        ITER(k + 1, aQ, aP, iQ, iP, wB0, wB1, wA0, wA1);
        ITER(k + 2, aR, aQ, iP, iQ, wA0, wA1, wB0, wB1);
        ITER(k + 3, aP, aR, iQ, iP, wB0, wB1, wA0, wA1);
        ITER(k + 4, aQ, aP, iP, iQ, wA0, wA1, wB0, wB1);
        ITER(k + 5, aR, aQ, iQ, iP, wB0, wB1, wA0, wA1);
    }
    ITER(24, aP, aR, iP, iQ, wA0, wA1, wB0, wB1);
    ITER(25, aQ, aP, iQ, iP, wB0, wB1, wA0, wA1);
    ITER(26, aR, aQ, iP, iQ, wA0, wA1, wB0, wB1);

    // ---------------- epilogue (C layout: col = l16, row = quad*4 + r) ----
    if (LAYER == 1) {
        u16* h = (u16*)out_;
        #pragma unroll
        for (int rt = 0; rt < 2; ++rt) {
            #pragma unroll
            for (int r = 0; r < 4; ++r) {
                size_t ro = (size_t)(rbase + rt * 16 + quad * 4 + r) * 64;
                #pragma unroll
                for (int nt = 0; nt < 3; ++nt) {
                    float x = acc[rt][nt][r];
                    float g = 0.5f * x * (1.0f + erff(x * 0.70710678118654752f));
                    h[ro + nt * 16 + l16] = f2bf(g);
                }
                h[ro + 48 + l16] = 0;      // zero pad cols 48..63
            }
        }
    } else {
        float* out = (float*)out_;
        #pragma unroll
        for (int rt = 0; rt < 2; ++rt) {
            #pragma unroll
            for (int nt = 0; nt < 3; ++nt) {
                int col = nt * 16 + l16;
                if (col < 38) {
                    #pragma unroll
                    for (int r = 0; r < 4; ++r) {
                        int row = rbase + rt * 16 + quad * 4 + r;
                        out[(size_t)row * 38 + col] = acc[rt][nt][r];
                    }
                }
            }
        }
    }
    #undef ITER
    #undef STAGE_W_LDS
    #undef GATHER
    #undef GATHER_BF16
    #undef GATHER_F32
}

// ---------------------------------------------------------------------------
extern "C" void kernel_launch(void* const* d_in, const int* in_sizes, int n_in,
                              void* d_out, int out_size, void* d_ws, size_t ws_size,
                              hipStream_t stream)
{
    const float* feat = (const float*)d_in[0];   // [N][64] fp32
    const int*   nbr  = (const int*)  d_in[1];   // [27][N] int32, N == pad idx
    const float* W1   = (const float*)d_in[2];   // [27][64][38]
    const float* W2   = (const float*)d_in[3];   // [27][38][38]

    const size_t hbytes = (size_t)(NPTS + 1) * 64 * 2;   // h incl. zero pad row
    const size_t wbytes = (size_t)K27 * WSTRIDE * 2;     // 221,184

    char* ws  = (char*)d_ws;
    u16* h    = (u16*)ws;
    u16* W1t  = (u16*)(ws + hbytes);
    u16* W2t  = (u16*)(ws + hbytes + wbytes);
    u16* Fb   = (u16*)(ws + hbytes + 2 * wbytes);
    const bool full = ws_size >= hbytes * 2 + 2 * wbytes;   // bf16 feature copy fits?

    prep_w<<<(K27 * 48 * 64 + 255) / 256, 256, 0, stream>>>(
        W1, W2, W1t, W2t,
        h + (size_t)NPTS * 64,
        full ? Fb + (size_t)NPTS * 64 : (u16*)nullptr);

    const int nblk = NPTS / 128;   // 3125, exact
    if (full) {
        prep_feat<<<(int)(((size_t)NPTS * 64 / 8 + 255) / 256), 256, 0, stream>>>(feat, Fb);
        spconv<1, true ><<<nblk, 256, 0, stream>>>(Fb,   nbr, W1t, h);
    } else {
        spconv<1, false><<<nblk, 256, 0, stream>>>(feat, nbr, W1t, h);
    }
    spconv<2, true ><<<nblk, 256, 0, stream>>>(h, nbr, W2t, d_out);
}

// Round 9
// 408.101 us; speedup vs baseline: 1.8782x; 1.0227x over previous
//
#include <hip/hip_runtime.h>
#include <math.h>

#define NPTS 400000
#define K27  27
#define WSTRIDE 4096   // shorts per k-tile in Wt (48*64=3072 used + pad -> 8KB)

typedef unsigned short u16;
typedef __bf16 bf16x8 __attribute__((ext_vector_type(8)));
typedef float  f32x4  __attribute__((ext_vector_type(4)));
typedef __attribute__((address_space(1))) void gvoid;
typedef __attribute__((address_space(3))) void lvoid;

__device__ __forceinline__ u16 f2bf(float f) {
    unsigned u = __float_as_uint(f);
    u += 0x7FFFu + ((u >> 16) & 1u);   // RNE round to bf16
    return (u16)(u >> 16);
}
__device__ __forceinline__ unsigned pack2(float lo, float hi) {
    return (unsigned)f2bf(lo) | ((unsigned)f2bf(hi) << 16);
}
__device__ __forceinline__ bf16x8 pack8(float4 x, float4 y) {
    union { uint4 u; bf16x8 v; } r;
    r.u.x = pack2(x.x, x.y); r.u.y = pack2(x.z, x.w);
    r.u.z = pack2(y.x, y.y); r.u.w = pack2(y.z, y.w);
    return r.v;
}
__device__ __forceinline__ bf16x8 zero8() {
    union { uint4 u; bf16x8 v; } r;
    r.u.x = 0; r.u.y = 0; r.u.z = 0; r.u.w = 0;
    return r.v;
}

// ---------------------------------------------------------------------------
// prep: W1 [27][64][38] / W2 [27][38][38] -> [27][WSTRIDE] bf16 tiles
// (48x64 n-major, zero-padded) with the LDS XOR-swizzle PRE-APPLIED:
//   short-offset o = n*64+kc stored at o ^ ((n&7)<<3).
// global_load_lds copies linearly; the kernel's ds_read applies the same XOR.
// Also zeroes the padding row (index NPTS) of h and Fb.
// ---------------------------------------------------------------------------
__global__ void prep_w(const float* __restrict__ W1, const float* __restrict__ W2,
                       u16* __restrict__ W1t, u16* __restrict__ W2t,
                       u16* __restrict__ hpad, u16* __restrict__ fpad)
{
    int i = blockIdx.x * 256 + threadIdx.x;
    if (i < 64) {                 // one 64-short row each
        hpad[i] = 0;
        if (fpad) fpad[i] = 0;
    }
    const int TOT = K27 * 48 * 64;
    if (i >= TOT) return;
    int k  = i / (48 * 64);
    int r  = i % (48 * 64);
    int n  = r >> 6;    // 0..47 (out channel)
    int kc = r & 63;    // 0..63 (in channel)
    u16 w1 = 0, w2 = 0;
    if (n < 38) {
        w1 = f2bf(W1[(k * 64 + kc) * 38 + n]);
        if (kc < 38) w2 = f2bf(W2[(k * 38 + kc) * 38 + n]);
    }
    int os = r ^ ((n & 7) << 3);          // pre-swizzled position
    W1t[k * WSTRIDE + os] = w1;
    W2t[k * WSTRIDE + os] = w2;
}

// ---------------------------------------------------------------------------
// prep: features fp32 [N][64] -> bf16 [N][64]  (8 elems / thread)
// ---------------------------------------------------------------------------
__global__ void prep_feat(const float* __restrict__ F, u16* __restrict__ Fb)
{
    size_t i = (size_t)blockIdx.x * 256 + threadIdx.x;
    const size_t TOT = (size_t)NPTS * 64 / 8;              // 3,200,000 exact
    if (i >= TOT) return;
    const float4* fp = (const float4*)(F + i * 8);
    float4 a = fp[0], b = fp[1];
    uint4 v;
    v.x = pack2(a.x, a.y); v.y = pack2(a.z, a.w);
    v.z = pack2(b.x, b.y); v.w = pack2(b.z, b.w);
    *(uint4*)(Fb + i * 8) = v;
}

// ---------------------------------------------------------------------------
// gather-GEMM layer. Round-9: k-PAIR super-iterations.
// One super-iter t covers k = 2t, 2t+1 with ONE barrier + ONE counted vmcnt:
//   r1: idx loads for ks{2t+4,2t+5} (4) + gather A ks{2t+2,2t+3} (8)
//   r2: [6 ds_read B_2t -> 12 MFMA] [6 ds_read B_2t+1 -> 12 MFMA]
//   r3: vmcnt(12): retires prev super's idx/A/W only; s_barrier
//   r4: stage W pair {2t+4,2t+5} -> wbuf[t&1]  (4 global_load_lds)
// 13.5 wait-events per block instead of 27; per-iter overhead amortized 2x.
// 32-bit-offset addressing (base+zext(u32)) for gather/idx to cut VALU.
// Block = 256 thr (4 waves) x 32 rows/wave = 128 rows; grid 3125 exact.
// LAYER==1: -> GELU -> h bf16 [N+1][64] (cols 48..63 zeroed)
// LAYER==2: -> fp32 out [N][38]
// ---------------------------------------------------------------------------
template<int LAYER, bool BF16IN>
__global__ __launch_bounds__(256, 3)
void spconv(const void* __restrict__ in_, const int* __restrict__ nbr,
            const u16* __restrict__ Wt, void* __restrict__ out_)
{
    __shared__ __align__(16) u16 wbuf[2][2][WSTRIDE];   // [pairbuf][tile] = 32 KB

    const int t    = threadIdx.x;
    const int wave = t >> 6;
    const int lane = t & 63;
    const int quad = lane >> 4;
    const int l16  = lane & 15;

    // bijective XCD-chunk swizzle (nwg=3125, nwg%8=5 -> m204 variant)
    int bid;
    {
        const int nwg = NPTS / 128, q = nwg / 8, r = nwg % 8;
        int x = blockIdx.x % 8, o = blockIdx.x / 8;
        bid = (x < r ? x * (q + 1) : r * (q + 1) + (x - r) * q) + o;
    }
    const int rbase = bid * 128 + wave * 32;   // 3125*128 == 400000
    const int swz   = (l16 & 7) << 3;          // B-read swizzle (shorts)

    f32x4 acc[2][3] = {};
    bf16x8 aP[2][2][2], aQ[2][2][2];   // [ks-in-pair][rt][khalf], 32 VGPR each
    int iP[2][2], iQ[2][2];            // [ks-in-pair][rt]

    // --- 32-bit-offset gather: off = idx*rowbytes + quad*16 (fits u32) ---
    #define GATHER_BF16(dst, ids)                                             \
        {                                                                     \
            const char* F8 = (const char*)in_;                                \
            _Pragma("unroll")                                                 \
            for (int ks = 0; ks < 2; ++ks)                                    \
            _Pragma("unroll")                                                 \
            for (int rt = 0; rt < 2; ++rt) {                                  \
                unsigned off = (unsigned)(ids)[ks][rt] * 128u                 \
                             + (unsigned)(quad * 16);                         \
                (dst)[ks][rt][0] = *(const bf16x8*)(F8 + off);                \
                (dst)[ks][rt][1] = *(const bf16x8*)(F8 + off + 64);           \
            }                                                                 \
        }
    #define GATHER_F32(dst, ids)                                              \
        {                                                                     \
            const char* F8 = (const char*)in_;                                \
            _Pragma("unroll")                                                 \
            for (int ks = 0; ks < 2; ++ks)                                    \
            _Pragma("unroll")                                                 \
            for (int rt = 0; rt < 2; ++rt) {                                  \
                if ((ids)[ks][rt] < NPTS) {                                   \
                    unsigned off = (unsigned)(ids)[ks][rt] * 256u             \
                                 + (unsigned)(quad * 32);                     \
                    float4 f0 = *(const float4*)(F8 + off);                   \
                    float4 f1 = *(const float4*)(F8 + off + 16);              \
                    float4 f2 = *(const float4*)(F8 + off + 128);             \
                    float4 f3 = *(const float4*)(F8 + off + 144);             \
                    (dst)[ks][rt][0] = pack8(f0, f1);                         \
                    (dst)[ks][rt][1] = pack8(f2, f3);                         \
                } else {                                                      \
                    (dst)[ks][rt][0] = zero8();                               \
                    (dst)[ks][rt][1] = zero8();                               \
                }                                                             \
            }                                                                 \
        }
    #define GATHER(dst, ids) { if (BF16IN) GATHER_BF16(dst, ids) else GATHER_F32(dst, ids) }

    // stage W tiles KW, KW+1 (clamped) into wbuf[BSEL][0/1]; 4 uniform glds
    #define STAGE_WPAIR(KW, BSEL)                                             \
        {                                                                     \
            int kk0 = (KW);     if (kk0 > K27 - 1) kk0 = K27 - 1;             \
            int kk1 = (KW) + 1; if (kk1 > K27 - 1) kk1 = K27 - 1;             \
            const u16* g0 = Wt + (size_t)kk0 * WSTRIDE + t * 8;               \
            const u16* g1 = Wt + (size_t)kk1 * WSTRIDE + t * 8;               \
            u16* l0 = &wbuf[(BSEL)][0][t * 8];                                \
            u16* l1 = &wbuf[(BSEL)][1][t * 8];                                \
            __builtin_amdgcn_global_load_lds((gvoid*)g0, (lvoid*)l0, 16,0,0); \
            __builtin_amdgcn_global_load_lds((gvoid*)(g0 + 2048),             \
                                             (lvoid*)(l0 + 2048), 16,0,0);    \
            __builtin_amdgcn_global_load_lds((gvoid*)g1, (lvoid*)l1, 16,0,0); \
            __builtin_amdgcn_global_load_lds((gvoid*)(g1 + 2048),             \
                                             (lvoid*)(l1 + 2048), 16,0,0);    \
        }

    // 6 ds_read + 12 MFMA for one k (tile TILE of pair-buffer BSEL)
    #define MFMA_K(APAIR, KS2, BSEL, TILE)                                    \
        {                                                                     \
            bf16x8 bfr[3][2];                                                 \
            const u16* wb = &wbuf[(BSEL)][(TILE)][0];                         \
            _Pragma("unroll")                                                 \
            for (int nt = 0; nt < 3; ++nt)                                    \
                _Pragma("unroll")                                             \
                for (int kq = 0; kq < 2; ++kq)                                \
                    bfr[nt][kq] = *(const bf16x8*)&wb[(nt * 16 + l16) * 64    \
                                        + ((kq * 32 + quad * 8) ^ swz)];      \
            __builtin_amdgcn_s_setprio(1);                                    \
            _Pragma("unroll")                                                 \
            for (int kq = 0; kq < 2; ++kq)                                    \
                _Pragma("unroll")                                             \
                for (int rt = 0; rt < 2; ++rt)                                \
                    _Pragma("unroll")                                         \
                    for (int nt = 0; nt < 3; ++nt)                            \
                        acc[rt][nt] = __builtin_amdgcn_mfma_f32_16x16x32_bf16(\
                            (APAIR)[KS2][rt][kq], bfr[nt][kq],                \
                            acc[rt][nt], 0, 0, 0);                           \
            __builtin_amdgcn_s_setprio(0);                                    \
        }

    // idx loads for ks {KF, KF+1} (clamped), 32-bit offsets
    #define LOAD_IDX(dst, KF)                                                 \
        {                                                                     \
            int kf0 = (KF);     if (kf0 > K27 - 1) kf0 = K27 - 1;             \
            int kf1 = (KF) + 1; if (kf1 > K27 - 1) kf1 = K27 - 1;             \
            const int kfs[2] = {kf0, kf1};                                    \
            _Pragma("unroll")                                                 \
            for (int ks = 0; ks < 2; ++ks)                                    \
            _Pragma("unroll")                                                 \
            for (int rt = 0; rt < 2; ++rt) {                                  \
                unsigned io = (unsigned)(kfs[ks] * NPTS + rbase + rt * 16     \
                                         + l16) * 4u;                         \
                (dst)[ks][rt] = *(const int*)((const char*)nbr + io);         \
            }                                                                 \
        }

    // ---------------- prologue ----------------
    LOAD_IDX(iP, 0);            // ks {0,1}
    GATHER(aP, iP);             // A_{0,1}
    LOAD_IDX(iQ, 2);            // ks {2,3}
    STAGE_WPAIR(0, 0);
    STAGE_WPAIR(2, 1);
    __builtin_amdgcn_sched_barrier(0);
    asm volatile("s_waitcnt vmcnt(0)" ::: "memory");
    __builtin_amdgcn_s_barrier();
    __builtin_amdgcn_sched_barrier(0);

    // ---------------- main loop: 13 super-iters (ks 0..25) ----------------
    #define SUPER(TT, ACUR, AISS, IUSE, ILOAD, BSEL)                          \
      {                                                                       \
        const int t_ = (TT);                                                  \
        /* r1: idx {2t+4,2t+5} + gather A {2t+2,2t+3} */                      \
        LOAD_IDX(ILOAD, 2 * t_ + 4);                                          \
        GATHER(AISS, IUSE);                                                   \
        __builtin_amdgcn_sched_barrier(0);                                    \
        /* r2: two k's of B-read + MFMA */                                    \
        MFMA_K(ACUR, 0, BSEL, 0);                                             \
        MFMA_K(ACUR, 1, BSEL, 1);                                             \
        __builtin_amdgcn_sched_barrier(0);                                    \
        /* r3: retire only prev super's loads; one barrier per pair */        \
        if (BF16IN) { asm volatile("s_waitcnt vmcnt(12)" ::: "memory"); }     \
        else        { asm volatile("s_waitcnt vmcnt(20)" ::: "memory"); }     \
        __builtin_amdgcn_s_barrier();                                         \
        __builtin_amdgcn_sched_barrier(0);                                    \
        /* r4: stage W pair {2t+4,2t+5} into the buffer just consumed */      \
        STAGE_WPAIR(2 * t_ + 4, BSEL);                                        \
        __builtin_amdgcn_sched_barrier(0);                                    \
      }

    for (int tt = 0; tt < 12; tt += 2) {
        SUPER(tt,     aP, aQ, iQ, iP, 0);
        SUPER(tt + 1, aQ, aP, iP, iQ, 1);
    }
    SUPER(12, aP, aQ, iQ, iP, 0);          // ks {24,25}; gathers A{26,26} into aQ

    // ---- tail: k = 26, A in aQ[0], W26 in wbuf[1][0] (staged at t=11) ----
    MFMA_K(aQ, 0, 1, 0);

    // ---------------- epilogue (C layout: col = l16, row = quad*4 + r) ----
    if (LAYER == 1) {
        u16* h = (u16*)out_;
        #pragma unroll
        for (int rt = 0; rt < 2; ++rt) {
            #pragma unroll
            for (int r = 0; r < 4; ++r) {
                size_t ro = (size_t)(rbase + rt * 16 + quad * 4 + r) * 64;
                #pragma unroll
                for (int nt = 0; nt < 3; ++nt) {
                    float x = acc[rt][nt][r];
                    float g = 0.5f * x * (1.0f + erff(x * 0.70710678118654752f));
                    h[ro + nt * 16 + l16] = f2bf(g);
                }
                h[ro + 48 + l16] = 0;      // zero pad cols 48..63
            }
        }
    } else {
        float* out = (float*)out_;
        #pragma unroll
        for (int rt = 0; rt < 2; ++rt) {
            #pragma unroll
            for (int nt = 0; nt < 3; ++nt) {
                int col = nt * 16 + l16;
                if (col < 38) {
                    #pragma unroll
                    for (int r = 0; r < 4; ++r) {
                        int row = rbase + rt * 16 + quad * 4 + r;
                        out[(size_t)row * 38 + col] = acc[rt][nt][r];
                    }
                }
            }
        }
    }
    #undef SUPER
    #undef LOAD_IDX
    #undef MFMA_K
    #undef STAGE_WPAIR
    #undef GATHER
    #undef GATHER_BF16
    #undef GATHER_F32
}

// ---------------------------------------------------------------------------
extern "C" void kernel_launch(void* const* d_in, const int* in_sizes, int n_in,
                              void* d_out, int out_size, void* d_ws, size_t ws_size,
                              hipStream_t stream)
{
    const float* feat = (const float*)d_in[0];   // [N][64] fp32
    const int*   nbr  = (const int*)  d_in[1];   // [27][N] int32, N == pad idx
    const float* W1   = (const float*)d_in[2];   // [27][64][38]
    const float* W2   = (const float*)d_in[3];   // [27][38][38]

    const size_t hbytes = (size_t)(NPTS + 1) * 64 * 2;   // h incl. zero pad row
    const size_t wbytes = (size_t)K27 * WSTRIDE * 2;     // 221,184

    char* ws  = (char*)d_ws;
    u16* h    = (u16*)ws;
    u16* W1t  = (u16*)(ws + hbytes);
    u16* W2t  = (u16*)(ws + hbytes + wbytes);
    u16* Fb   = (u16*)(ws + hbytes + 2 * wbytes);
    const bool full = ws_size >= hbytes * 2 + 2 * wbytes;   // bf16 feature copy fits?

    prep_w<<<(K27 * 48 * 64 + 255) / 256, 256, 0, stream>>>(
        W1, W2, W1t, W2t,
        h + (size_t)NPTS * 64,
        full ? Fb + (size_t)NPTS * 64 : (u16*)nullptr);

    const int nblk = NPTS / 128;   // 3125, exact
    if (full) {
        prep_feat<<<(int)(((size_t)NPTS * 64 / 8 + 255) / 256), 256, 0, stream>>>(feat, Fb);
        spconv<1, true ><<<nblk, 256, 0, stream>>>(Fb,   nbr, W1t, h);
    } else {
        spconv<1, false><<<nblk, 256, 0, stream>>>(feat, nbr, W1t, h);
    }
    spconv<2, true ><<<nblk, 256, 0, stream>>>(h, nbr, W2t, d_out);
}

// Round 10
// 383.988 us; speedup vs baseline: 1.9961x; 1.0628x over previous
//
#include <hip/hip_runtime.h>
#include <math.h>

#define NPTS  400000
#define K27   27
#define TILEB 4864            // bytes per W k-tile: 38 rows x 128 B (pre-swizzled)
#define NTP   9               // tiles per LDS pass
#define PASSB (NTP * TILEB)   // 43,776 B
#define ZOFFB PASSB           // zero block offset
#define LDSB  (PASSB + 2048)  // 45,824 B

typedef unsigned short u16;
typedef __bf16 bf16x8 __attribute__((ext_vector_type(8)));
typedef float  f32x4  __attribute__((ext_vector_type(4)));

__device__ __forceinline__ u16 f2bf(float f) {
    unsigned u = __float_as_uint(f);
    u += 0x7FFFu + ((u >> 16) & 1u);   // RNE round to bf16
    return (u16)(u >> 16);
}
__device__ __forceinline__ unsigned pack2(float lo, float hi) {
    return (unsigned)f2bf(lo) | ((unsigned)f2bf(hi) << 16);
}
__device__ __forceinline__ bf16x8 pack8(float4 x, float4 y) {
    union { uint4 u; bf16x8 v; } r;
    r.u.x = pack2(x.x, x.y); r.u.y = pack2(x.z, x.w);
    r.u.z = pack2(y.x, y.y); r.u.w = pack2(y.z, y.w);
    return r.v;
}
__device__ __forceinline__ bf16x8 zero8() {
    union { uint4 u; bf16x8 v; } r;
    r.u.x = 0; r.u.y = 0; r.u.z = 0; r.u.w = 0;
    return r.v;
}

// ---------------------------------------------------------------------------
// prep: W1 [27][64][38] / W2 [27][38][38] -> [27][38][64] bf16 tiles
// (n-major rows, k-contig cols, XOR-swizzle pre-applied within each row:
//  short col kc stored at kc ^ ((n&7)<<3)). 4864 B per tile, 131,328 B total.
// Also zeroes the padding row (index NPTS) of h and Fb.
// ---------------------------------------------------------------------------
__global__ void prep_w(const float* __restrict__ W1, const float* __restrict__ W2,
                       u16* __restrict__ W1t, u16* __restrict__ W2t,
                       u16* __restrict__ hpad, u16* __restrict__ fpad)
{
    int i = blockIdx.x * 256 + threadIdx.x;
    if (i < 64) {                 // one 64-short row each
        hpad[i] = 0;
        if (fpad) fpad[i] = 0;
    }
    const int TOT = K27 * 38 * 64;
    if (i >= TOT) return;
    int k  = i / (38 * 64);
    int r  = i % (38 * 64);
    int n  = r >> 6;    // 0..37 (out channel)
    int kc = r & 63;    // 0..63 (in channel)
    u16 w1 = f2bf(W1[(k * 64 + kc) * 38 + n]);
    u16 w2 = (kc < 38) ? f2bf(W2[(k * 38 + kc) * 38 + n]) : (u16)0;
    int os = (n << 6) | (kc ^ ((n & 7) << 3));   // pre-swizzled position
    W1t[k * 2432 + os] = w1;
    W2t[k * 2432 + os] = w2;
}

// ---------------------------------------------------------------------------
// prep: features fp32 [N][64] -> bf16 [N][64]  (8 elems / thread)
// ---------------------------------------------------------------------------
__global__ void prep_feat(const float* __restrict__ F, u16* __restrict__ Fb)
{
    size_t i = (size_t)blockIdx.x * 256 + threadIdx.x;
    const size_t TOT = (size_t)NPTS * 64 / 8;              // 3,200,000 exact
    if (i >= TOT) return;
    const float4* fp = (const float4*)(F + i * 8);
    float4 a = fp[0], b = fp[1];
    uint4 v;
    v.x = pack2(a.x, a.y); v.y = pack2(a.z, a.w);
    v.z = pack2(b.x, b.y); v.w = pack2(b.z, b.w);
    *(uint4*)(Fb + i * 8) = v;
}

// ---------------------------------------------------------------------------
// gather-GEMM layer. Round-10: W fully LDS-resident in 3 passes of 9 tiles.
//   - k-loop is BARRIER-FREE and explicit-vmcnt-free: per k just
//     {idx_{k+2} load; gather A_{k+1} (reg ping/pong); 6 ds_read B; 12 MFMA;
//      advance 6 B-addresses by kstep}. Compiler-managed in-order waits give
//     A a full iteration of slack (nothing younger is ever waited on).
//   - 2 stage-swap barrier pairs per block total (vs 27 per-k barriers).
//   - Zero rows n=38..47 redirect to a shared 2KB zero block (kstep=0).
// Block = 512 thr (8 waves) x 32 rows/wave = 256 rows; grid 1563 (row-clamped).
// __launch_bounds__(512,4) -> <=128 VGPR, 2 blocks/CU, 4 waves/SIMD.
// LAYER==1: -> GELU -> h bf16 [N+1][64] (cols 48..63 zeroed)
// LAYER==2: -> fp32 out [N][38]
// ---------------------------------------------------------------------------
template<int LAYER, bool BF16IN>
__global__ __launch_bounds__(512, 4)
void spconv(const void* __restrict__ in_, const int* __restrict__ nbr,
            const u16* __restrict__ Wt, void* __restrict__ out_)
{
    __shared__ __align__(16) char wlds[LDSB];

    const int t    = threadIdx.x;
    const int wave = t >> 6;
    const int lane = t & 63;
    const int quad = lane >> 4;
    const int l16  = lane & 15;

    // bijective XCD-chunk swizzle (nwg=1563, m204 variant)
    int bid;
    {
        const int nwg = (NPTS + 255) / 256, q = nwg / 8, r = nwg % 8;
        int x = blockIdx.x % 8, o = blockIdx.x / 8;
        bid = (x < r ? x * (q + 1) : r * (q + 1) + (x - r) * q) + o;
    }
    const int rbase = bid * 256 + wave * 32;

    // clamped per-lane row offsets for idx loads (grid overruns NPTS by 128)
    int roff[2];
    #pragma unroll
    for (int rt = 0; rt < 2; ++rt) {
        int rr = rbase + rt * 16 + l16;
        roff[rt] = rr < NPTS ? rr : NPTS - 1;
    }

    // B addressing: 6 running byte-addresses + per-nt kstep
    const int swz = (l16 & 7) << 3;
    unsigned bbase[3][2], ca[3][2], kst[3];
    #pragma unroll
    for (int nt = 0; nt < 3; ++nt) {
        int n = nt * 16 + l16;
        bool v = n < 38;
        unsigned rowb = v ? (unsigned)(n * 128) : (unsigned)(ZOFFB + l16 * 128);
        kst[nt] = v ? (unsigned)TILEB : 0u;
        #pragma unroll
        for (int kq = 0; kq < 2; ++kq)
            bbase[nt][kq] = rowb + (unsigned)((((kq * 32 + quad * 8) ^ swz)) * 2);
    }

    f32x4 acc[2][3] = {};
    bf16x8 aP[2][2], aQ[2][2];
    int iP[2], iQ[2];

    #define GATHER_BF16(dst, ids)                                             \
        {                                                                     \
            const u16* F = (const u16*)in_;                                   \
            _Pragma("unroll")                                                 \
            for (int rt = 0; rt < 2; ++rt) {                                  \
                const u16* rowp = F + (size_t)(ids)[rt] * 64 + quad * 8;      \
                (dst)[rt][0] = *(const bf16x8*)(rowp);                        \
                (dst)[rt][1] = *(const bf16x8*)(rowp + 32);                   \
            }                                                                 \
        }
    #define GATHER_F32(dst, ids)                                              \
        {                                                                     \
            const float* F = (const float*)in_;                               \
            _Pragma("unroll")                                                 \
            for (int rt = 0; rt < 2; ++rt) {                                  \
                if ((ids)[rt] < NPTS) {                                       \
                    const float* rowp = F + (size_t)(ids)[rt] * 64 + quad * 8;\
                    float4 f0 = *(const float4*)(rowp);                       \
                    float4 f1 = *(const float4*)(rowp + 4);                   \
                    float4 f2 = *(const float4*)(rowp + 32);                  \
                    float4 f3 = *(const float4*)(rowp + 36);                  \
                    (dst)[rt][0] = pack8(f0, f1);                             \
                    (dst)[rt][1] = pack8(f2, f3);                             \
                } else {                                                      \
                    (dst)[rt][0] = zero8();                                   \
                    (dst)[rt][1] = zero8();                                   \
                }                                                             \
            }                                                                 \
        }
    #define GATHER(dst, ids) { if (BF16IN) GATHER_BF16(dst, ids) else GATHER_F32(dst, ids) }

    // stage 9 tiles (43,776 B) from Wt + PIDX*PASSB into wlds (reg-staged)
    #define STAGE(PIDX)                                                       \
        {                                                                     \
            const char* src = (const char*)Wt + (size_t)(PIDX) * PASSB;       \
            _Pragma("unroll")                                                 \
            for (int o = 0; o < 6; ++o) {                                     \
                int off = t * 16 + o * 512 * 16;                              \
                if (off < PASSB)                                              \
                    *(uint4*)(wlds + off) = *(const uint4*)(src + off);       \
            }                                                                 \
        }

    // ---------------- prologue ----------------
    #pragma unroll
    for (int rt = 0; rt < 2; ++rt) iP[rt] = nbr[roff[rt]];                // idx0
    GATHER(aP, iP);                                                       // A_0
    #pragma unroll
    for (int rt = 0; rt < 2; ++rt) iQ[rt] = nbr[(size_t)NPTS + roff[rt]]; // idx1
    STAGE(0);
    if (t < 128) { uint4 z; z.x = z.y = z.z = z.w = 0;
                   *(uint4*)(wlds + ZOFFB + t * 16) = z; }
    __builtin_amdgcn_sched_barrier(0);
    asm volatile("s_waitcnt lgkmcnt(0)" ::: "memory");   // ds_writes landed
    __builtin_amdgcn_s_barrier();                        // publish; gathers fly
    __builtin_amdgcn_sched_barrier(0);
    #pragma unroll
    for (int nt = 0; nt < 3; ++nt) { ca[nt][0] = bbase[nt][0]; ca[nt][1] = bbase[nt][1]; }

    // ---------------- barrier-free ITER ----------------
    #define ITER(KK, ACUR, ANXT, ICUR, INXT)                                  \
      {                                                                       \
        const int kf_ = ((KK) + 2 > K27 - 1) ? K27 - 1 : (KK) + 2;            \
        _Pragma("unroll")                                                     \
        for (int rt = 0; rt < 2; ++rt)                                        \
            INXT[rt] = nbr[(size_t)kf_ * NPTS + roff[rt]];                    \
        GATHER(ANXT, ICUR);                                                   \
        bf16x8 bfr[3][2];                                                     \
        _Pragma("unroll")                                                     \
        for (int nt = 0; nt < 3; ++nt)                                        \
            _Pragma("unroll")                                                 \
            for (int kq = 0; kq < 2; ++kq)                                    \
                bfr[nt][kq] = *(const bf16x8*)(wlds + ca[nt][kq]);            \
        __builtin_amdgcn_sched_barrier(0);                                    \
        __builtin_amdgcn_s_setprio(1);                                        \
        _Pragma("unroll")                                                     \
        for (int kq = 0; kq < 2; ++kq)                                        \
            _Pragma("unroll")                                                 \
            for (int rt = 0; rt < 2; ++rt)                                    \
                _Pragma("unroll")                                             \
                for (int nt = 0; nt < 3; ++nt)                                \
                    acc[rt][nt] = __builtin_amdgcn_mfma_f32_16x16x32_bf16(    \
                        ACUR[rt][kq], bfr[nt][kq], acc[rt][nt], 0, 0, 0);     \
        __builtin_amdgcn_s_setprio(0);                                        \
        __builtin_amdgcn_sched_barrier(0);                                    \
        _Pragma("unroll")                                                     \
        for (int nt = 0; nt < 3; ++nt) {                                      \
            ca[nt][0] += kst[nt]; ca[nt][1] += kst[nt];                       \
        }                                                                     \
      }
    #define ITER_E(KK) ITER(KK, aP, aQ, iQ, iP)
    #define ITER_O(KK) ITER(KK, aQ, aP, iP, iQ)

    // pass swap: all waves done reading -> restage -> publish; A gathers fly
    #define PASSSWAP(PIDX)                                                    \
        __builtin_amdgcn_sched_barrier(0);                                    \
        __builtin_amdgcn_s_barrier();                                         \
        STAGE(PIDX);                                                          \
        __builtin_amdgcn_sched_barrier(0);                                    \
        asm volatile("s_waitcnt lgkmcnt(0)" ::: "memory");                    \
        __builtin_amdgcn_s_barrier();                                         \
        __builtin_amdgcn_sched_barrier(0);                                    \
        _Pragma("unroll")                                                     \
        for (int nt = 0; nt < 3; ++nt) {                                      \
            ca[nt][0] = bbase[nt][0]; ca[nt][1] = bbase[nt][1];               \
        }

    // pass 0: k = 0..8
    ITER_E(0) ITER_O(1) ITER_E(2) ITER_O(3) ITER_E(4)
    ITER_O(5) ITER_E(6) ITER_O(7) ITER_E(8)
    PASSSWAP(1)
    // pass 1: k = 9..17
    ITER_O(9) ITER_E(10) ITER_O(11) ITER_E(12) ITER_O(13)
    ITER_E(14) ITER_O(15) ITER_E(16) ITER_O(17)
    PASSSWAP(2)
    // pass 2: k = 18..25, tail k = 26
    ITER_E(18) ITER_O(19) ITER_E(20) ITER_O(21) ITER_E(22)
    ITER_O(23) ITER_E(24) ITER_O(25)
    {   // tail k = 26: A in aP (gathered at k=25), tile 8 of pass 2
        bf16x8 bfr[3][2];
        #pragma unroll
        for (int nt = 0; nt < 3; ++nt)
            #pragma unroll
            for (int kq = 0; kq < 2; ++kq)
                bfr[nt][kq] = *(const bf16x8*)(wlds + ca[nt][kq]);
        #pragma unroll
        for (int kq = 0; kq < 2; ++kq)
            #pragma unroll
            for (int rt = 0; rt < 2; ++rt)
                #pragma unroll
                for (int nt = 0; nt < 3; ++nt)
                    acc[rt][nt] = __builtin_amdgcn_mfma_f32_16x16x32_bf16(
                        aP[rt][kq], bfr[nt][kq], acc[rt][nt], 0, 0, 0);
    }

    // ---------------- epilogue (C layout: col = l16, row = quad*4 + r) ----
    if (LAYER == 1) {
        u16* h = (u16*)out_;
        #pragma unroll
        for (int rt = 0; rt < 2; ++rt) {
            #pragma unroll
            for (int r = 0; r < 4; ++r) {
                int row = rbase + rt * 16 + quad * 4 + r;
                if (row < NPTS) {
                    size_t ro = (size_t)row * 64;
                    #pragma unroll
                    for (int nt = 0; nt < 3; ++nt) {
                        float x = acc[rt][nt][r];
                        float g = 0.5f * x * (1.0f + erff(x * 0.70710678118654752f));
                        h[ro + nt * 16 + l16] = f2bf(g);
                    }
                    h[ro + 48 + l16] = 0;      // zero pad cols 48..63
                }
            }
        }
    } else {
        float* out = (float*)out_;
        #pragma unroll
        for (int rt = 0; rt < 2; ++rt) {
            #pragma unroll
            for (int nt = 0; nt < 3; ++nt) {
                int col = nt * 16 + l16;
                if (col < 38) {
                    #pragma unroll
                    for (int r = 0; r < 4; ++r) {
                        int row = rbase + rt * 16 + quad * 4 + r;
                        if (row < NPTS)
                            out[(size_t)row * 38 + col] = acc[rt][nt][r];
                    }
                }
            }
        }
    }
    #undef PASSSWAP
    #undef ITER_O
    #undef ITER_E
    #undef ITER
    #undef STAGE
    #undef GATHER
    #undef GATHER_BF16
    #undef GATHER_F32
}

// ---------------------------------------------------------------------------
extern "C" void kernel_launch(void* const* d_in, const int* in_sizes, int n_in,
                              void* d_out, int out_size, void* d_ws, size_t ws_size,
                              hipStream_t stream)
{
    const float* feat = (const float*)d_in[0];   // [N][64] fp32
    const int*   nbr  = (const int*)  d_in[1];   // [27][N] int32, N == pad idx
    const float* W1   = (const float*)d_in[2];   // [27][64][38]
    const float* W2   = (const float*)d_in[3];   // [27][38][38]

    const size_t hbytes = (size_t)(NPTS + 1) * 64 * 2;   // h incl. zero pad row
    const size_t wbytes = (size_t)K27 * 2432 * 2;        // 131,328

    char* ws  = (char*)d_ws;
    u16* h    = (u16*)ws;
    u16* W1t  = (u16*)(ws + hbytes);
    u16* W2t  = (u16*)(ws + hbytes + wbytes);
    u16* Fb   = (u16*)(ws + hbytes + 2 * wbytes);
    const bool full = ws_size >= hbytes * 2 + 2 * wbytes;   // bf16 feature copy fits?

    prep_w<<<(K27 * 38 * 64 + 255) / 256, 256, 0, stream>>>(
        W1, W2, W1t, W2t,
        h + (size_t)NPTS * 64,
        full ? Fb + (size_t)NPTS * 64 : (u16*)nullptr);

    const int nblk = (NPTS + 255) / 256;   // 1563
    if (full) {
        prep_feat<<<(int)(((size_t)NPTS * 64 / 8 + 255) / 256), 256, 0, stream>>>(feat, Fb);
        spconv<1, true ><<<nblk, 512, 0, stream>>>(Fb,   nbr, W1t, h);
    } else {
        spconv<1, false><<<nblk, 512, 0, stream>>>(feat, nbr, W1t, h);
    }
    spconv<2, true ><<<nblk, 512, 0, stream>>>(h, nbr, W2t, d_out);
}